// Round 5
// baseline (102.292 us; speedup 1.0000x reference)
//
#include <hip/hip_runtime.h>
#include <stdint.h>

#define CI 256
#define CO 256
#define HW 4096          // 64*64 pixels per image
#define PXT 32           // pixels per block (two MFMA m-tiles)
#define QP 264           // LDS Q row pitch in shorts (16B-aligned rows)

typedef __attribute__((ext_vector_type(8))) short short8;   // 8 bf16 = 4 VGPRs
typedef __attribute__((ext_vector_type(4))) float float4v;  // MFMA C/D frag

// ---------- weight prep: fp32 -> bf16 (RNE) + per-row fp32 sums ----------
__global__ void prep_kernel(const float* __restrict__ w,
                            ushort* __restrict__ w16,
                            float* __restrict__ wsum) {
    const int o = blockIdx.x;        // one output row per 64-thread block
    const int lane = threadIdx.x;    // 0..63
    float4 v = ((const float4*)(w + o * CI))[lane];
    auto cvt = [](float f) -> ushort {
        uint32_t u = __float_as_uint(f);
        return (ushort)((u + 0x7FFFu + ((u >> 16) & 1u)) >> 16);   // RNE
    };
    ushort4 q;
    q.x = cvt(v.x); q.y = cvt(v.y); q.z = cvt(v.z); q.w = cvt(v.w);
    ((ushort4*)(w16 + o * CI))[lane] = q;
    float s = v.x + v.y + v.z + v.w;
    for (int off = 32; off >= 1; off >>= 1) s += __shfl_down(s, off);
    if (lane == 0) wsum[o] = s;
}

// ---------- fused: x read ONCE -> min/max -> quantize -> MFMA GEMM ----------
// block = 32 px x 256 out-ch (1024 blocks, pinned 4/CU); wave = 32 px x 64 ch.
// MFMA 16x16x32: A = quantized pixels, B = bf16 weights.
// A-frag A[m=lane&15][k=quad*8+j]; D: col(lane&15)=ch, row(quad*4+reg)=pixel.
__global__ __launch_bounds__(256, 4)
void noise_conv_kernel(const float* __restrict__ x,
                       const ushort* __restrict__ w16,
                       const float* __restrict__ wsum,
                       const float* __restrict__ bias,
                       float* __restrict__ out) {
    __shared__ ushort Q[PXT * QP];             // ~16.9 KB quantized bf16 tile
    __shared__ float Rmn[4][33], Rmx[4][33];   // per-wave per-pixel partials
    __shared__ float cmin_s[PXT], s_s[PXT];

    const int t = threadIdx.x;
    const int blk = blockIdx.x;                // 1024 = 8 img * 128 tiles
    const int img = blk >> 7;
    const int p0 = (blk & 127) * PXT;
    const float* xb = x + (size_t)img * CI * HW + p0;

    const int p = t & 31;                      // this thread's pixel (0..31)
    const int cg = t >> 5;                     // channel group (32 ch), 0..7
    const int l = t & 63;
    const int wv = t >> 6;

    // ---- load this thread's 32 channels of its pixel (x read once) ----
    float xv[32];
    #pragma unroll
    for (int j = 0; j < 32; ++j)
        xv[j] = xb[(size_t)(cg * 32 + j) * HW + p];

    // ---- per-pixel min/max: 31 local pairs + lane^32 fold + 4-way LDS ----
    float mn = xv[0], mx = xv[0];
    #pragma unroll
    for (int j = 1; j < 32; ++j) { mn = fminf(mn, xv[j]); mx = fmaxf(mx, xv[j]); }
    mn = fminf(mn, __shfl_xor(mn, 32));        // fold the wave's 2 ch-groups
    mx = fmaxf(mx, __shfl_xor(mx, 32));
    if (l < 32) { Rmn[wv][l] = mn; Rmx[wv][l] = mx; }
    __syncthreads();
    if (t < 32) {
        float m0 = Rmn[0][t], m1 = Rmx[0][t];
        #pragma unroll
        for (int s = 1; s < 4; ++s) {
            m0 = fminf(m0, Rmn[s][t]);
            m1 = fmaxf(m1, Rmx[s][t]);
        }
        cmin_s[t] = m0;
        s_s[t] = (m1 - m0) / 63.0f;            // match ref: /63
    }
    __syncthreads();

    // ---- quantize in 4 chunks of 8 ch (short pk live range), stage to LDS ----
    {
        const float cm = cmin_s[p];
        const float iv = 1.0f / s_s[p];
        ushort* qrow = Q + p * QP + cg * 32;
        #pragma unroll
        for (int c4 = 0; c4 < 4; ++c4) {
            uint32_t pk[4];
            #pragma unroll
            for (int j2 = 0; j2 < 4; ++j2) {
                const float q0 = rintf((xv[c4 * 8 + 2 * j2]     - cm) * iv);
                const float q1 = rintf((xv[c4 * 8 + 2 * j2 + 1] - cm) * iv);
                pk[j2] = (__float_as_uint(q0) >> 16) |
                         (__float_as_uint(q1) & 0xFFFF0000u);   // exact bf16
            }
            ((uint4*)qrow)[c4] = make_uint4(pk[0], pk[1], pk[2], pk[3]);
        }
    }

    // ---- prefetch k=0 weight frags (independent of LDS; hides L2 latency) ----
    const int m16 = l & 15;
    const int quad = l >> 4;
    const ushort* wrow = w16 + (size_t)(wv * 64) * CI;
    short8 bfc[4];
    #pragma unroll
    for (int nt = 0; nt < 4; ++nt)
        bfc[nt] = *((const short8*)(
            wrow + (size_t)(nt * 16 + m16) * CI + quad * 8));
    __syncthreads();

    // ---- K-loop: A from LDS (2 m-tiles), B from L2-resident weights ----
    float4v acc[2][4];
    #pragma unroll
    for (int mt = 0; mt < 2; ++mt)
        #pragma unroll
        for (int nt = 0; nt < 4; ++nt) {
            float4v z = {0.0f, 0.0f, 0.0f, 0.0f};
            acc[mt][nt] = z;
        }

    {   // ks = 0 with prefetched B
        short8 af[2];
        #pragma unroll
        for (int mt = 0; mt < 2; ++mt)
            af[mt] = *((const short8*)(Q + (mt * 16 + m16) * QP + quad * 8));
        #pragma unroll
        for (int nt = 0; nt < 4; ++nt)
            #pragma unroll
            for (int mt = 0; mt < 2; ++mt)
                acc[mt][nt] = __builtin_amdgcn_mfma_f32_16x16x32_bf16(
                    af[mt], bfc[nt], acc[mt][nt], 0, 0, 0);
    }
    #pragma unroll
    for (int ks = 1; ks < 8; ++ks) {
        short8 af[2];
        #pragma unroll
        for (int mt = 0; mt < 2; ++mt)
            af[mt] = *((const short8*)(
                Q + (mt * 16 + m16) * QP + ks * 32 + quad * 8));
        #pragma unroll
        for (int nt = 0; nt < 4; ++nt) {
            const short8 bf = *((const short8*)(
                wrow + (size_t)(nt * 16 + m16) * CI + ks * 32 + quad * 8));
            #pragma unroll
            for (int mt = 0; mt < 2; ++mt)
                acc[mt][nt] = __builtin_amdgcn_mfma_f32_16x16x32_bf16(
                    af[mt], bf, acc[mt][nt], 0, 0, 0);
        }
    }

    // ---- epilogue: rescale + cmin*wsum + bias, float4 stores ----
    float* outp = out + (size_t)img * CO * HW + p0;
    #pragma unroll
    for (int mt = 0; mt < 2; ++mt) {
        const int pb = mt * 16 + quad * 4;     // pixel base for D rows 0..3
        float sv[4], cv[4];
        #pragma unroll
        for (int r = 0; r < 4; ++r) {
            sv[r] = s_s[pb + r];
            cv[r] = cmin_s[pb + r];
        }
        #pragma unroll
        for (int nt = 0; nt < 4; ++nt) {
            const int ch = wv * 64 + nt * 16 + m16;
            const float ws = wsum[ch];
            const float bs = bias[ch];
            float4 o;
            o.x = acc[mt][nt][0] * sv[0] + cv[0] * ws + bs;
            o.y = acc[mt][nt][1] * sv[1] + cv[1] * ws + bs;
            o.z = acc[mt][nt][2] * sv[2] + cv[2] * ws + bs;
            o.w = acc[mt][nt][3] * sv[3] + cv[3] * ws + bs;
            *((float4*)(outp + (size_t)ch * HW + pb)) = o;
        }
    }
}

extern "C" void kernel_launch(void* const* d_in, const int* in_sizes, int n_in,
                              void* d_out, int out_size, void* d_ws, size_t ws_size,
                              hipStream_t stream) {
    const float* x    = (const float*)d_in[0];
    const float* w    = (const float*)d_in[1];
    const float* bias = (const float*)d_in[2];
    float* out = (float*)d_out;

    ushort* w16 = (ushort*)d_ws;                                   // 128 KiB
    float* wsum = (float*)((char*)d_ws + (size_t)CO * CI * sizeof(ushort));

    prep_kernel<<<CO, 64, 0, stream>>>(w, w16, wsum);
    noise_conv_kernel<<<1024, 256, 0, stream>>>(x, w16, wsum, bias, out);
}

// Round 6
// 101.644 us; speedup vs baseline: 1.0064x; 1.0064x over previous
//
#include <hip/hip_runtime.h>
#include <stdint.h>

#define CI 256
#define CO 256
#define HW 4096          // 64*64 pixels per image
#define PXT 32           // pixels per tile (two MFMA m-tiles)
#define QP 264           // LDS Q row pitch in shorts (16B-aligned rows)

typedef __attribute__((ext_vector_type(8))) short short8;   // 8 bf16 = 4 VGPRs
typedef __attribute__((ext_vector_type(4))) float float4v;  // MFMA C/D frag

// ---------- weight prep: fp32 -> bf16 (RNE) + per-row fp32 sums ----------
__global__ void prep_kernel(const float* __restrict__ w,
                            ushort* __restrict__ w16,
                            float* __restrict__ wsum) {
    const int o = blockIdx.x;        // one output row per 64-thread block
    const int lane = threadIdx.x;    // 0..63
    float4 v = ((const float4*)(w + o * CI))[lane];
    auto cvt = [](float f) -> ushort {
        uint32_t u = __float_as_uint(f);
        return (ushort)((u + 0x7FFFu + ((u >> 16) & 1u)) >> 16);   // RNE
    };
    ushort4 q;
    q.x = cvt(v.x); q.y = cvt(v.y); q.z = cvt(v.z); q.w = cvt(v.w);
    ((ushort4*)(w16 + o * CI))[lane] = q;
    float s = v.x + v.y + v.z + v.w;
    for (int off = 32; off >= 1; off >>= 1) s += __shfl_down(s, off);
    if (lane == 0) wsum[o] = s;
}

// ---------- fused, tile-pipelined: 2 tiles/block, x loads issued up front ----
// block = 2 x (32 px x 256 out-ch); grid 512 (2 blocks/CU); wave = 32px x 64ch.
// MFMA 16x16x32: A = quantized pixels, B = bf16 weights.
// A-frag A[m=lane&15][k=quad*8+j]; D: col(lane&15)=ch, row(quad*4+reg)=pixel.
__global__ __launch_bounds__(256, 2)
void noise_conv_kernel(const float* __restrict__ x,
                       const ushort* __restrict__ w16,
                       const float* __restrict__ wsum,
                       const float* __restrict__ bias,
                       float* __restrict__ out) {
    __shared__ ushort Q[PXT * QP];             // ~16.9 KB quantized bf16 tile
    __shared__ float Rmn[4][33], Rmx[4][33];   // per-wave per-pixel partials
    __shared__ float cmin_s[PXT], s_s[PXT];

    const int t = threadIdx.x;
    const int blk = blockIdx.x;                // 512 = 8 img * 64 tile-pairs
    const int img = blk >> 6;
    const int p0b = (blk & 63) * 64;           // pair covers pixels [p0b, p0b+64)
    const float* xb = x + (size_t)img * CI * HW;
    float* outb = out + (size_t)img * CO * HW;

    const int p = t & 31;                      // this thread's pixel-in-tile
    const int cg = t >> 5;                     // channel group (32 ch), 0..7
    const int l = t & 63;
    const int wv = t >> 6;
    const int m16 = l & 15;
    const int quad = l >> 4;

    // ---- issue BOTH tiles' x loads up front (vmcnt retires in order:
    //      first use of tile 0 waits only for its own 32 loads; tile 1's
    //      drain overlaps tile 0's reduce/MFMA/store phases) ----
    float xv[2][32];
    #pragma unroll
    for (int h = 0; h < 2; ++h)
        #pragma unroll
        for (int j = 0; j < 32; ++j)
            xv[h][j] = xb[(size_t)(cg * 32 + j) * HW + p0b + h * 32 + p];

    #pragma unroll
    for (int h = 0; h < 2; ++h) {
        const int p0 = p0b + h * 32;

        // ---- per-pixel min/max: 31 local pairs + lane^32 fold + 4-way LDS
        float mn = xv[h][0], mx = xv[h][0];
        #pragma unroll
        for (int j = 1; j < 32; ++j) {
            mn = fminf(mn, xv[h][j]);
            mx = fmaxf(mx, xv[h][j]);
        }
        mn = fminf(mn, __shfl_xor(mn, 32));    // fold the wave's 2 ch-groups
        mx = fmaxf(mx, __shfl_xor(mx, 32));
        if (l < 32) { Rmn[wv][l] = mn; Rmx[wv][l] = mx; }
        __syncthreads();
        if (t < 32) {
            float m0 = Rmn[0][t], m1 = Rmx[0][t];
            #pragma unroll
            for (int s = 1; s < 4; ++s) {
                m0 = fminf(m0, Rmn[s][t]);
                m1 = fmaxf(m1, Rmx[s][t]);
            }
            cmin_s[t] = m0;
            s_s[t] = (m1 - m0) / 63.0f;        // match ref: /63
        }
        __syncthreads();

        // ---- quantize in 4 chunks of 8 ch, stage bf16 to LDS ----
        {
            const float cm = cmin_s[p];
            const float iv = 1.0f / s_s[p];
            ushort* qrow = Q + p * QP + cg * 32;
            #pragma unroll
            for (int c4 = 0; c4 < 4; ++c4) {
                uint32_t pk[4];
                #pragma unroll
                for (int j2 = 0; j2 < 4; ++j2) {
                    const float q0 = rintf((xv[h][c4 * 8 + 2 * j2]     - cm) * iv);
                    const float q1 = rintf((xv[h][c4 * 8 + 2 * j2 + 1] - cm) * iv);
                    pk[j2] = (__float_as_uint(q0) >> 16) |
                             (__float_as_uint(q1) & 0xFFFF0000u);   // exact bf16
                }
                ((uint4*)qrow)[c4] = make_uint4(pk[0], pk[1], pk[2], pk[3]);
            }
        }
        __syncthreads();

        // ---- K-loop: A from LDS (2 m-tiles), B from L2-resident weights ----
        float4v acc[2][4];
        #pragma unroll
        for (int mt = 0; mt < 2; ++mt)
            #pragma unroll
            for (int nt = 0; nt < 4; ++nt) {
                float4v z = {0.0f, 0.0f, 0.0f, 0.0f};
                acc[mt][nt] = z;
            }
        const ushort* wrow = w16 + (size_t)(wv * 64) * CI;
        #pragma unroll
        for (int ks = 0; ks < 8; ++ks) {
            short8 af[2];
            #pragma unroll
            for (int mt = 0; mt < 2; ++mt)
                af[mt] = *((const short8*)(
                    Q + (mt * 16 + m16) * QP + ks * 32 + quad * 8));
            #pragma unroll
            for (int nt = 0; nt < 4; ++nt) {
                const short8 bf = *((const short8*)(
                    wrow + (size_t)(nt * 16 + m16) * CI + ks * 32 + quad * 8));
                #pragma unroll
                for (int mt = 0; mt < 2; ++mt)
                    acc[mt][nt] = __builtin_amdgcn_mfma_f32_16x16x32_bf16(
                        af[mt], bf, acc[mt][nt], 0, 0, 0);
            }
        }

        // ---- epilogue: rescale + cmin*wsum + bias, float4 stores ----
        // (no extra barrier before next tile: its first LDS writes are Rmn/Rmx,
        //  which every thread finished reading before this tile's barrier 2)
        #pragma unroll
        for (int mt = 0; mt < 2; ++mt) {
            const int pb = mt * 16 + quad * 4; // pixel base for D rows 0..3
            float sv[4], cv[4];
            #pragma unroll
            for (int r = 0; r < 4; ++r) {
                sv[r] = s_s[pb + r];
                cv[r] = cmin_s[pb + r];
            }
            #pragma unroll
            for (int nt = 0; nt < 4; ++nt) {
                const int ch = wv * 64 + nt * 16 + m16;
                const float ws = wsum[ch];
                const float bs = bias[ch];
                float4 o;
                o.x = acc[mt][nt][0] * sv[0] + cv[0] * ws + bs;
                o.y = acc[mt][nt][1] * sv[1] + cv[1] * ws + bs;
                o.z = acc[mt][nt][2] * sv[2] + cv[2] * ws + bs;
                o.w = acc[mt][nt][3] * sv[3] + cv[3] * ws + bs;
                *((float4*)(outb + (size_t)ch * HW + p0 + pb)) = o;
            }
        }
        if (h == 0) __syncthreads();   // protect s_s/cmin_s reads above from
                                       // tile 1's barrier-2 writers racing ahead
    }
}

extern "C" void kernel_launch(void* const* d_in, const int* in_sizes, int n_in,
                              void* d_out, int out_size, void* d_ws, size_t ws_size,
                              hipStream_t stream) {
    const float* x    = (const float*)d_in[0];
    const float* w    = (const float*)d_in[1];
    const float* bias = (const float*)d_in[2];
    float* out = (float*)d_out;

    ushort* w16 = (ushort*)d_ws;                                   // 128 KiB
    float* wsum = (float*)((char*)d_ws + (size_t)CO * CI * sizeof(ushort));

    prep_kernel<<<CO, 64, 0, stream>>>(w, w16, wsum);
    noise_conv_kernel<<<512, 256, 0, stream>>>(x, w16, wsum, bias, out);
}